// Round 8
// baseline (1839.411 us; speedup 1.0000x reference)
//
#include <hip/hip_runtime.h>
#include <stdint.h>

typedef short bf16x8 __attribute__((ext_vector_type(8)));
typedef float f32x4  __attribute__((ext_vector_type(4)));
typedef uint32_t u32;

#define NSAMP  32768
#define D      512
#define RPB    8
#define NLAYER 7
#define KSN    16
#define WL_U32 131072                // u32 per packed layer

union U4B { uint4 u; u32 w[4]; bf16x8 s; };
__device__ __forceinline__ bf16x8 as_frag(uint4 v) { U4B c; c.u = v; return c.s; }

__device__ __forceinline__ u32 bfr(float f) {               // RNE bf16 bits
    u32 b = __float_as_uint(f);
    return (b + 0x7fffu + ((b >> 16) & 1u)) >> 16;
}
__device__ __forceinline__ float bf2f(u32 h) { return __uint_as_float(h << 16); }
__device__ __forceinline__ u32 packpair(float v) {          // hi | lo<<16
    u32 h = bfr(v);
    u32 l = bfr(v - bf2f(h));
    return h | (l << 16);
}
__device__ __forceinline__ float fast_tanh(float z) {       // inf-safe both tails
    const float e = __expf(2.f * z);
    return 1.f - 2.f / (e + 1.f);
}

// ---- prep: pack Wh[L][k][n] -> B-fragment-ordered bf16 hi/lo tensors ----
// 16B unit idx4 = ((L*16+ks)*512 + n)*4 + half ; holds k = ks*32+half*8+{0..7}, col n
__global__ void pack_weights(const float* __restrict__ Wh,
                             u32* __restrict__ whi, u32* __restrict__ wlo) {
    const int L    = blockIdx.x >> 4;
    const int ks   = blockIdx.x & 15;
    const int lane = threadIdx.x & 63;
    const int half = threadIdx.x >> 6;                       // 0..3
    const float* src = Wh + (size_t)L * D * D + (size_t)(ks * 32 + half * 8) * D;
    for (int nb = 0; nb < D; nb += 64) {
        const int n = nb + lane;
        float v[8];
        #pragma unroll
        for (int i = 0; i < 8; ++i) v[i] = src[(size_t)i * D + n];
        u32 hi[4], lo[4];
        #pragma unroll
        for (int j = 0; j < 4; ++j) {
            u32 h0 = bfr(v[2*j]),   l0 = bfr(v[2*j]   - bf2f(h0));
            u32 h1 = bfr(v[2*j+1]), l1 = bfr(v[2*j+1] - bf2f(h1));
            hi[j] = h0 | (h1 << 16);
            lo[j] = l0 | (l1 << 16);
        }
        const size_t idx4 = (size_t)((L * 16 + ks) * 512 + n) * 4 + half;
        *(uint4*)(whi + idx4 * 4) = *(uint4*)hi;
        *(uint4*)(wlo + idx4 * 4) = *(uint4*)lo;
    }
}

// ---- main: 512-thr blocks, RPB=8. tile0 = rows h(0-7)|J0(8-15) [3-product],
// tile1 = J1(0-7)|J2(8-15) [2-product]. 8 waves x 64 cols. 51 KB LDS -> 2 blocks/CU:
// block A's epilogue overlaps block B's K-loop (independent barriers).
__global__ __launch_bounds__(512, 4)
void mlp_curl_mfma(const float* __restrict__ x,
                   const float* __restrict__ W0,
                   const float* __restrict__ b0,
                   const float* __restrict__ bhid,
                   const float* __restrict__ Wf,
                   const u32* __restrict__ whi,
                   const u32* __restrict__ wlo,
                   float* __restrict__ out)
{
    // A fragments in MFMA order: uint4 index (tile*16+ks)*64 + fraglane,
    // fraglane = (k>>3)*16 + row ; within uint4, bf16 for k&7 at byte (k&7)*2.
    __shared__ uint4 AHi[2048];      // 32 KB: tile0 + tile1
    __shared__ uint4 ALo[1024];      // 16 KB: tile0 lo only
    __shared__ float JT[768];        //  3 KB: per-wave Jout partials

    const int t    = threadIdx.x;
    const int g    = t >> 6, lane = t & 63;
    const int lrow = lane & 15, lq = lane >> 4;
    const int c0   = g * 64;                  // wave's col base (64 cols)
    const int n0   = blockIdx.x * RPB;

    // ---------- init: wave g fills both tiles for ks = 2g, 2g+1 ----------
    {
        const int r = lrow;                   // row within tile
        const float4 xv = *(const float4*)(x + (size_t)(n0 + (r & 7)) * 4);
        #pragma unroll
        for (int ksl = 0; ksl < 2; ++ksl) {
            const int ks = g * 2 + ksl;
            const int cb = ks * 32 + lq * 8;
            float v0[8], v1[8];
            #pragma unroll
            for (int j = 0; j < 8; ++j) {
                const int c = cb + j;
                const float w0 = W0[c], w1 = W0[D + c], w2 = W0[2*D + c], w3 = W0[3*D + c];
                v0[j] = (r < 8) ? (b0[c] + xv.x*w0 + xv.y*w1 + xv.z*w2 + xv.w*w3) : w0;
                v1[j] = (r < 8) ? w1 : w2;
            }
            u32 pp[8];
            #pragma unroll
            for (int j = 0; j < 8; ++j) pp[j] = packpair(v0[j]);
            uint4 hi, lo;
            hi.x = (pp[0] & 0xffffu) | (pp[1] << 16);  lo.x = (pp[0] >> 16) | (pp[1] & 0xffff0000u);
            hi.y = (pp[2] & 0xffffu) | (pp[3] << 16);  lo.y = (pp[2] >> 16) | (pp[3] & 0xffff0000u);
            hi.z = (pp[4] & 0xffffu) | (pp[5] << 16);  lo.z = (pp[4] >> 16) | (pp[5] & 0xffff0000u);
            hi.w = (pp[6] & 0xffffu) | (pp[7] << 16);  lo.w = (pp[6] >> 16) | (pp[7] & 0xffff0000u);
            AHi[ks * 64 + lane] = hi;
            ALo[ks * 64 + lane] = lo;
            uint4 h1;
            h1.x = bfr(v1[0]) | (bfr(v1[1]) << 16);
            h1.y = bfr(v1[2]) | (bfr(v1[3]) << 16);
            h1.z = bfr(v1[4]) | (bfr(v1[5]) << 16);
            h1.w = bfr(v1[6]) | (bfr(v1[7]) << 16);
            AHi[(16 + ks) * 64 + lane] = h1;
        }
    }
    __syncthreads();

    // per-lane B offsets (u32 units) within a ks-slab for the wave's 4 col-tiles
    u32 boff[4];
    #pragma unroll
    for (int ct = 0; ct < 4; ++ct)
        boff[ct] = ((u32)(c0 + ct * 16 + lrow) * 4 + (u32)lq) * 4;

    for (int L = 0; L < NLAYER; ++L) {
        const u32* __restrict__ whiL = whi + (size_t)L * WL_U32;
        const u32* __restrict__ wloL = wlo + (size_t)L * WL_U32;
        f32x4 acc[2][4];
        #pragma unroll
        for (int ct = 0; ct < 4; ++ct) { acc[0][ct] = (f32x4)0.f; acc[1][ct] = (f32x4)0.f; }

        #pragma unroll 2
        for (int ks = 0; ks < KSN; ++ks) {
            const bf16x8 a0h = as_frag(AHi[ks * 64 + lane]);
            const bf16x8 a0l = as_frag(ALo[ks * 64 + lane]);
            const bf16x8 a1h = as_frag(AHi[(16 + ks) * 64 + lane]);
            const size_t off = (size_t)ks * 8192;
            #pragma unroll
            for (int ct = 0; ct < 4; ++ct) {
                const bf16x8 bh = as_frag(*(const uint4*)(whiL + off + boff[ct]));
                const bf16x8 bl = as_frag(*(const uint4*)(wloL + off + boff[ct]));
                acc[0][ct] = __builtin_amdgcn_mfma_f32_16x16x32_bf16(a0l, bh, acc[0][ct], 0, 0, 0);
                acc[0][ct] = __builtin_amdgcn_mfma_f32_16x16x32_bf16(a0h, bl, acc[0][ct], 0, 0, 0);
                acc[0][ct] = __builtin_amdgcn_mfma_f32_16x16x32_bf16(a0h, bh, acc[0][ct], 0, 0, 0);
                acc[1][ct] = __builtin_amdgcn_mfma_f32_16x16x32_bf16(a1h, bl, acc[1][ct], 0, 0, 0);
                acc[1][ct] = __builtin_amdgcn_mfma_f32_16x16x32_bf16(a1h, bh, acc[1][ct], 0, 0, 0);
            }
        }
        __syncthreads();                 // all A-frag reads of layer L done

        // epilogue: tanh (lanes<32 own h rows), tp broadcast via shfl, scatter
        float tpv[4][4];
        #pragma unroll
        for (int ct = 0; ct < 4; ++ct) {
            const int col  = c0 + ct * 16 + lrow;
            const float bias = bhid[(size_t)L * D + col];
            const int ks_s = g * 2 + (ct >> 1);
            const int k_in = (ct & 1) * 16 + lrow;
            #pragma unroll
            for (int q = 0; q < 4; ++q) {
                const float z0 = acc[0][ct][q];
                const float h  = fast_tanh(z0 + bias);
                const float tv = __shfl((1.f - h) * (1.f + h), lane & 31);
                tpv[ct][q] = tv;
                if (L < NLAYER - 1) {
                    // tile0: h (lanes<32) or J0 = z0*tp (lanes>=32), hi+lo
                    const float v0 = (lane < 32) ? h : z0 * tv;
                    const u32 pp = packpair(v0);
                    const u32 fl = (u32)(((k_in >> 3) * 16) + lq * 4 + q);
                    const u32 b0b = ((u32)(ks_s * 64) + fl) * 16 + ((u32)(k_in & 7) << 1);
                    *(uint16_t*)((char*)AHi + b0b) = (uint16_t)(pp & 0xffffu);
                    *(uint16_t*)((char*)ALo + b0b) = (uint16_t)(pp >> 16);
                    // tile1: J1 (lanes<32) / J2 (lanes>=32) = z1*tp, hi only
                    const float v1 = acc[1][ct][q] * tv;
                    const u32 b1b = ((u32)((16 + ks_s) * 64) + fl) * 16 + ((u32)(k_in & 7) << 1);
                    *(uint16_t*)((char*)AHi + b1b) = (uint16_t)bfr(v1);
                }
            }
        }

        if (L == NLAYER - 1) {           // final: Jout partials over wave's 64 cols
            #pragma unroll
            for (int i = 0; i < 3; ++i) {
                float Jr[4][4];
                #pragma unroll
                for (int q = 0; q < 4; ++q)
                    #pragma unroll
                    for (int o = 0; o < 4; ++o) Jr[q][o] = 0.f;
                #pragma unroll
                for (int ct = 0; ct < 4; ++ct) {
                    const int col = c0 + ct * 16 + lrow;
                    const float4 wf = *(const float4*)(Wf + (size_t)col * 4);
                    #pragma unroll
                    for (int q = 0; q < 4; ++q) {
                        float jv;
                        if (i == 0)      jv = (lane >= 32) ? acc[0][ct][q] * tpv[ct][q] : 0.f;
                        else if (i == 1) jv = (lane <  32) ? acc[1][ct][q] * tpv[ct][q] : 0.f;
                        else             jv = (lane >= 32) ? acc[1][ct][q] * tpv[ct][q] : 0.f;
                        Jr[q][0] += jv * wf.x;
                        Jr[q][1] += jv * wf.y;
                        Jr[q][2] += jv * wf.z;
                        Jr[q][3] += jv * wf.w;
                    }
                }
                #pragma unroll
                for (int m = 1; m <= 8; m <<= 1)
                    #pragma unroll
                    for (int q = 0; q < 4; ++q)
                        #pragma unroll
                        for (int o = 0; o < 4; ++o)
                            Jr[q][o] += __shfl_xor(Jr[q][o], m);
                const bool wr = (i == 1) ? (lq < 2) : (lq >= 2);
                if (lrow == 0 && wr) {
                    #pragma unroll
                    for (int q = 0; q < 4; ++q) {
                        const int s = (lq & 1) * 4 + q;
                        *(float4*)&JT[((g * 3 + i) * 8 + s) * 4] =
                            make_float4(Jr[q][0], Jr[q][1], Jr[q][2], Jr[q][3]);
                    }
                }
            }
        }
        __syncthreads();                 // scatter / JT writes visible
    }

    // ---------- curl combination (sum JT over the 8 waves) ----------
    if (t < RPB * 6) {
        const int s = t / 6, c = t % 6;
        float J[3][4];
        #pragma unroll
        for (int i = 0; i < 3; ++i)
            #pragma unroll
            for (int o = 0; o < 4; ++o) {
                float v = 0.f;
                for (int w = 0; w < 8; ++w) v += JT[((w * 3 + i) * 8 + s) * 4 + o];
                J[i][o] = v;
            }
        float v;
        if      (c == 0) v = J[1][2] - J[2][1];
        else if (c == 1) v = J[2][0] - J[0][2];
        else if (c == 2) v = J[0][1] - J[1][0];
        else if (c == 3) v = J[0][3];
        else if (c == 4) v = J[1][3];
        else             v = J[2][3];
        out[(size_t)(n0 + s) * 6 + c] = v;
    }
}

extern "C" void kernel_launch(void* const* d_in, const int* in_sizes, int n_in,
                              void* d_out, int out_size, void* d_ws, size_t ws_size,
                              hipStream_t stream) {
    const float* x  = (const float*)d_in[0];
    const float* W0 = (const float*)d_in[1];
    const float* b0 = (const float*)d_in[2];
    const float* Wh = (const float*)d_in[3];
    const float* bh = (const float*)d_in[4];
    const float* Wf = (const float*)d_in[5];
    u32* whi = (u32*)d_ws;
    u32* wlo = whi + (size_t)NLAYER * WL_U32;
    pack_weights<<<NLAYER * 16, 256, 0, stream>>>(Wh, whi, wlo);
    mlp_curl_mfma<<<NSAMP / RPB, 512, 0, stream>>>(x, W0, b0, bh, Wf, whi, wlo, (float*)d_out);
}

// Round 9
// 1007.531 us; speedup vs baseline: 1.8257x; 1.8257x over previous
//
#include <hip/hip_runtime.h>
#include <stdint.h>

typedef short bf16x8 __attribute__((ext_vector_type(8)));
typedef float f32x4  __attribute__((ext_vector_type(4)));
typedef uint32_t u32;

#define NSAMP  32768
#define D      512
#define RPB    16
#define NLAYER 7
#define KSN    16
#define WL_U32 131072                // u32 per packed layer

union U4B { uint4 u; u32 w[4]; bf16x8 s; };
__device__ __forceinline__ bf16x8 as_frag(uint4 v) { U4B c; c.u = v; return c.s; }

__device__ __forceinline__ u32 bfr(float f) {               // RNE bf16 bits
    u32 b = __float_as_uint(f);
    return (b + 0x7fffu + ((b >> 16) & 1u)) >> 16;
}
__device__ __forceinline__ float bf2f(u32 h) { return __uint_as_float(h << 16); }
__device__ __forceinline__ u32 packpair(float v) {          // hi | lo<<16
    u32 h = bfr(v);
    u32 l = bfr(v - bf2f(h));
    return h | (l << 16);
}
__device__ __forceinline__ float fast_tanh(float z) {       // inf-safe both tails
    const float e = __expf(2.f * z);
    return 1.f - 2.f / (e + 1.f);
}

// ---- prep: pack Wh[L][k][n] -> B-fragment-ordered bf16 hi/lo tensors ----
// 16B unit idx4 = ((L*16+ks)*512 + n)*4 + half ; holds k = ks*32+half*8+{0..7}, col n
__global__ void pack_weights(const float* __restrict__ Wh,
                             u32* __restrict__ whi, u32* __restrict__ wlo) {
    const int L    = blockIdx.x >> 4;
    const int ks   = blockIdx.x & 15;
    const int lane = threadIdx.x & 63;
    const int half = threadIdx.x >> 6;                       // 0..3
    const float* src = Wh + (size_t)L * D * D + (size_t)(ks * 32 + half * 8) * D;
    for (int nb = 0; nb < D; nb += 64) {
        const int n = nb + lane;
        float v[8];
        #pragma unroll
        for (int i = 0; i < 8; ++i) v[i] = src[(size_t)i * D + n];
        u32 hi[4], lo[4];
        #pragma unroll
        for (int j = 0; j < 4; ++j) {
            u32 h0 = bfr(v[2*j]),   l0 = bfr(v[2*j]   - bf2f(h0));
            u32 h1 = bfr(v[2*j+1]), l1 = bfr(v[2*j+1] - bf2f(h1));
            hi[j] = h0 | (h1 << 16);
            lo[j] = l0 | (l1 << 16);
        }
        const size_t idx4 = (size_t)((L * 16 + ks) * 512 + n) * 4 + half;
        *(uint4*)(whi + idx4 * 4) = *(uint4*)hi;
        *(uint4*)(wlo + idx4 * 4) = *(uint4*)lo;
    }
}

// ---- main: 512-thr blocks, RPB=16. 8 waves x 64 cols; each wave computes ALL
// 4 row-tiles (h 3-product; J0,J1,J2 2-product) for its cols -> tanh' handoff is
// same-lane (no shfl). LDS 80 KB -> 2 blocks/CU with independent barriers;
// B-reuse identical to round 7 (2048 blocks, 4.5 MFMA per 16B load).
__global__ __launch_bounds__(512, 4)
void mlp_curl_mfma(const float* __restrict__ x,
                   const float* __restrict__ W0,
                   const float* __restrict__ b0,
                   const float* __restrict__ bhid,
                   const float* __restrict__ Wf,
                   const u32* __restrict__ whi,
                   const u32* __restrict__ wlo,
                   float* __restrict__ out)
{
    // A fragments in MFMA order: uint4 index (tile*16+ks)*64 + fraglane,
    // fraglane = (k>>3)*16 + row ; within uint4, bf16 for k&7 at byte (k&7)*2.
    __shared__ uint4 AHi[4096];      // 64 KB: tiles 0..3 = h, J0, J1, J2 (hi)
    __shared__ uint4 ALo[1024];      // 16 KB: tile0 (h) lo only

    const int t    = threadIdx.x;
    const int g    = t >> 6, lane = t & 63;
    const int lrow = lane & 15, lq = lane >> 4;
    const int c0   = g * 64;                  // wave's col base (64 cols)
    const int n0   = blockIdx.x * RPB;

    // ---------- init: wave g fills ks = 2g, 2g+1 for all 4 tiles ----------
    {
        const float4 xv = *(const float4*)(x + (size_t)(n0 + lrow) * 4);
        #pragma unroll
        for (int ksl = 0; ksl < 2; ++ksl) {
            const int ks = g * 2 + ksl;
            const int cb = ks * 32 + lq * 8;
            // tile0: h0 = x@W0 + b0 (no tanh), hi+lo
            {
                u32 pp[8];
                #pragma unroll
                for (int j = 0; j < 8; ++j) {
                    const int c = cb + j;
                    const float v = b0[c] + xv.x * W0[c]         + xv.y * W0[D + c]
                                          + xv.z * W0[2 * D + c] + xv.w * W0[3 * D + c];
                    pp[j] = packpair(v);
                }
                uint4 hi, lo;
                hi.x = (pp[0] & 0xffffu) | (pp[1] << 16);  lo.x = (pp[0] >> 16) | (pp[1] & 0xffff0000u);
                hi.y = (pp[2] & 0xffffu) | (pp[3] << 16);  lo.y = (pp[2] >> 16) | (pp[3] & 0xffff0000u);
                hi.z = (pp[4] & 0xffffu) | (pp[5] << 16);  lo.z = (pp[4] >> 16) | (pp[5] & 0xffff0000u);
                hi.w = (pp[6] & 0xffffu) | (pp[7] << 16);  lo.w = (pp[6] >> 16) | (pp[7] & 0xffff0000u);
                AHi[ks * 64 + lane] = hi;
                ALo[ks * 64 + lane] = lo;
            }
            // tiles 1..3: Ji = W0 row i (same for all 16 tile-rows), hi only
            #pragma unroll
            for (int i = 0; i < 3; ++i) {
                const float* wr = W0 + (size_t)i * D;
                uint4 hi;
                hi.x = bfr(wr[cb + 0]) | (bfr(wr[cb + 1]) << 16);
                hi.y = bfr(wr[cb + 2]) | (bfr(wr[cb + 3]) << 16);
                hi.z = bfr(wr[cb + 4]) | (bfr(wr[cb + 5]) << 16);
                hi.w = bfr(wr[cb + 6]) | (bfr(wr[cb + 7]) << 16);
                AHi[((i + 1) * 16 + ks) * 64 + lane] = hi;
            }
        }
    }
    __syncthreads();

    // per-lane B offsets (u32 units) within a ks-slab for the wave's 4 col-tiles
    u32 boff[4];
    #pragma unroll
    for (int ct = 0; ct < 4; ++ct)
        boff[ct] = ((u32)(c0 + ct * 16 + lrow) * 4 + (u32)lq) * 4;

    for (int L = 0; L < NLAYER; ++L) {
        const u32* __restrict__ whiL = whi + (size_t)L * WL_U32;
        const u32* __restrict__ wloL = wlo + (size_t)L * WL_U32;
        f32x4 acc[4][4];                       // [tile][ct]
        #pragma unroll
        for (int R = 0; R < 4; ++R)
            #pragma unroll
            for (int ct = 0; ct < 4; ++ct) acc[R][ct] = (f32x4)0.f;

        #pragma unroll 2
        for (int ks = 0; ks < KSN; ++ks) {
            const bf16x8 a0h = as_frag(AHi[ks * 64 + lane]);
            const bf16x8 a0l = as_frag(ALo[ks * 64 + lane]);
            const bf16x8 a1h = as_frag(AHi[(16 + ks) * 64 + lane]);
            const bf16x8 a2h = as_frag(AHi[(32 + ks) * 64 + lane]);
            const bf16x8 a3h = as_frag(AHi[(48 + ks) * 64 + lane]);
            const size_t off = (size_t)ks * 8192;
            #pragma unroll
            for (int ct = 0; ct < 4; ++ct) {
                const bf16x8 bh = as_frag(*(const uint4*)(whiL + off + boff[ct]));
                const bf16x8 bl = as_frag(*(const uint4*)(wloL + off + boff[ct]));
                acc[0][ct] = __builtin_amdgcn_mfma_f32_16x16x32_bf16(a0l, bh, acc[0][ct], 0, 0, 0);
                acc[0][ct] = __builtin_amdgcn_mfma_f32_16x16x32_bf16(a0h, bl, acc[0][ct], 0, 0, 0);
                acc[0][ct] = __builtin_amdgcn_mfma_f32_16x16x32_bf16(a0h, bh, acc[0][ct], 0, 0, 0);
                acc[1][ct] = __builtin_amdgcn_mfma_f32_16x16x32_bf16(a1h, bl, acc[1][ct], 0, 0, 0);
                acc[1][ct] = __builtin_amdgcn_mfma_f32_16x16x32_bf16(a1h, bh, acc[1][ct], 0, 0, 0);
                acc[2][ct] = __builtin_amdgcn_mfma_f32_16x16x32_bf16(a2h, bl, acc[2][ct], 0, 0, 0);
                acc[2][ct] = __builtin_amdgcn_mfma_f32_16x16x32_bf16(a2h, bh, acc[2][ct], 0, 0, 0);
                acc[3][ct] = __builtin_amdgcn_mfma_f32_16x16x32_bf16(a3h, bl, acc[3][ct], 0, 0, 0);
                acc[3][ct] = __builtin_amdgcn_mfma_f32_16x16x32_bf16(a3h, bh, acc[3][ct], 0, 0, 0);
            }
        }
        __syncthreads();                 // all A-frag reads of layer L done

        // epilogue: tanh + tanh' all same-lane; scatter into own ks slabs
        float tpv[4][4];
        #pragma unroll
        for (int ct = 0; ct < 4; ++ct) {
            const int col  = c0 + ct * 16 + lrow;
            const float bias = bhid[(size_t)L * D + col];
            const int ks_s = g * 2 + (ct >> 1);
            const int k_in = (ct & 1) * 16 + lrow;
            #pragma unroll
            for (int q = 0; q < 4; ++q) {
                const float z0 = acc[0][ct][q];
                const float h  = fast_tanh(z0 + bias);
                const float tv = (1.f - h) * (1.f + h);
                tpv[ct][q] = tv;
                if (L < NLAYER - 1) {
                    const u32 fl  = (u32)(((k_in >> 3) * 16) + lq * 4 + q);
                    const u32 bas = ((u32)(ks_s * 64) + fl) * 16 + ((u32)(k_in & 7) << 1);
                    const u32 pp  = packpair(h);
                    *(uint16_t*)((char*)AHi + bas) = (uint16_t)(pp & 0xffffu);
                    *(uint16_t*)((char*)ALo + bas) = (uint16_t)(pp >> 16);
                    #pragma unroll
                    for (int i = 1; i < 4; ++i) {
                        const u32 bb = ((u32)((i * 16 + ks_s) * 64) + fl) * 16 + ((u32)(k_in & 7) << 1);
                        *(uint16_t*)((char*)AHi + bb) = (uint16_t)bfr(acc[i][ct][q] * tv);
                    }
                }
            }
        }

        if (L == NLAYER - 1) {           // final: Jout partials over wave's 64 cols
            #pragma unroll
            for (int i = 0; i < 3; ++i) {
                float Jr[4][4];
                #pragma unroll
                for (int q = 0; q < 4; ++q)
                    #pragma unroll
                    for (int o = 0; o < 4; ++o) Jr[q][o] = 0.f;
                #pragma unroll
                for (int ct = 0; ct < 4; ++ct) {
                    const int col = c0 + ct * 16 + lrow;
                    const float4 wf = *(const float4*)(Wf + (size_t)col * 4);
                    #pragma unroll
                    for (int q = 0; q < 4; ++q) {
                        const float jv = acc[i + 1][ct][q] * tpv[ct][q];
                        Jr[q][0] += jv * wf.x;
                        Jr[q][1] += jv * wf.y;
                        Jr[q][2] += jv * wf.z;
                        Jr[q][3] += jv * wf.w;
                    }
                }
                #pragma unroll
                for (int m = 1; m <= 8; m <<= 1)
                    #pragma unroll
                    for (int q = 0; q < 4; ++q)
                        #pragma unroll
                        for (int o = 0; o < 4; ++o)
                            Jr[q][o] += __shfl_xor(Jr[q][o], m);
                if (lrow == 0) {         // JT[g][i][s][o] in dead AHi space (6 KB)
                    float* JT = (float*)AHi;
                    #pragma unroll
                    for (int q = 0; q < 4; ++q) {
                        const int s = lq * 4 + q;
                        *(float4*)&JT[((g * 3 + i) * 16 + s) * 4] =
                            make_float4(Jr[q][0], Jr[q][1], Jr[q][2], Jr[q][3]);
                    }
                }
            }
        }
        __syncthreads();                 // scatter / JT writes visible
    }

    // ---------- curl combination (sum JT over the 8 waves) ----------
    if (t < RPB * 6) {
        const float* JT = (const float*)AHi;
        const int s = t / 6, c = t % 6;
        float J[3][4];
        #pragma unroll
        for (int i = 0; i < 3; ++i)
            #pragma unroll
            for (int o = 0; o < 4; ++o) {
                float v = 0.f;
                for (int w = 0; w < 8; ++w) v += JT[((w * 3 + i) * 16 + s) * 4 + o];
                J[i][o] = v;
            }
        float v;
        if      (c == 0) v = J[1][2] - J[2][1];
        else if (c == 1) v = J[2][0] - J[0][2];
        else if (c == 2) v = J[0][1] - J[1][0];
        else if (c == 3) v = J[0][3];
        else if (c == 4) v = J[1][3];
        else             v = J[2][3];
        out[(size_t)(n0 + s) * 6 + c] = v;
    }
}

extern "C" void kernel_launch(void* const* d_in, const int* in_sizes, int n_in,
                              void* d_out, int out_size, void* d_ws, size_t ws_size,
                              hipStream_t stream) {
    const float* x  = (const float*)d_in[0];
    const float* W0 = (const float*)d_in[1];
    const float* b0 = (const float*)d_in[2];
    const float* Wh = (const float*)d_in[3];
    const float* bh = (const float*)d_in[4];
    const float* Wf = (const float*)d_in[5];
    u32* whi = (u32*)d_ws;
    u32* wlo = whi + (size_t)NLAYER * WL_U32;
    pack_weights<<<NLAYER * 16, 256, 0, stream>>>(Wh, whi, wlo);
    mlp_curl_mfma<<<NSAMP / RPB, 512, 0, stream>>>(x, W0, b0, bh, Wf, whi, wlo, (float*)d_out);
}